// Round 19
// baseline (121.261 us; speedup 1.0000x reference)
//
#include <hip/hip_runtime.h>

// z_e: [B=64, D=64, H=64, W=64] fp32 ; embeddings: [K=512, D=64] fp32
// out: z_q_st [64,64,64,64] fp32 ++ loss (1 fp32)
constexpr int Dc  = 64;
constexpr int Kc  = 512;
constexpr int HWc = 4096;
constexpr int Nc  = 64 * HWc;                    // 262144 points
constexpr float INV_ELEMS = 1.0f / 16777216.0f;
// fp16 1-term metric: s = eh.zh - ||e||^2/2. FLAG_HALF = 0.02 ~ 7.8 sigma of
// the pairwise error; flagged points get exact fp32 rescan. Rate ~1.5%.
constexpr float FLAG_HALF = 0.02f;

constexpr int LDS_EPOS = 65536;                  // vq_main: after 64KB E-fp16
constexpr int LDS_RED  = LDS_EPOS + 2048;
constexpr int LDS_TOT  = LDS_RED + 64;           // 67648 B -> 2 blocks/CU

constexpr int FX_EPOS  = 131072;                 // vq_fixup: after 128KB E-fp32
constexpr int FX_TOT   = FX_EPOS + 2048;         // 133120 B -> 1 block/CU

constexpr int WL_H_OFF = 69632;                  // headers: {oldidx, point} u64
constexpr int WL_Z_OFF = WL_H_OFF + 262144;      // stashed z: 64 f32 per entry

typedef __attribute__((ext_vector_type(8))) _Float16 half8;
typedef __attribute__((ext_vector_type(4))) float    f32x4;

static __device__ __forceinline__ short f2h(float x) {   // RNE fp32->fp16
    _Float16 h = (_Float16)x;
    return __builtin_bit_cast(short, h);
}

// ---- K1: prep — pack E-fp16 fragment stream (64KB) + eposneg ---------------
__global__ __launch_bounds__(256) void vq_prep(const float* __restrict__ emb,
                                               short* __restrict__ EF,
                                               float* __restrict__ eposneg) {
    int q = blockIdx.x * 256 + threadIdx.x;
    if (q < 4096) {
        int kt = q >> 7, c = (q >> 6) & 1, lane = q & 63;
        int code = kt * 16 + (lane & 15);
        int d0   = c * 32 + (lane >> 4) * 8;
        const float* e = emb + (size_t)code * Dc + d0;
        short v[8];
#pragma unroll
        for (int j = 0; j < 8; ++j) v[j] = f2h(e[j]);
        *reinterpret_cast<int4*>(EF + (size_t)q * 8) = *reinterpret_cast<int4*>(v);
    } else if (q < 4096 + Kc) {
        int k = q - 4096;
        const float* e = emb + (size_t)k * Dc;
        float s0 = 0.f, s1 = 0.f, s2 = 0.f, s3 = 0.f;
#pragma unroll
        for (int d = 0; d < 16; ++d) {
            float v0 = e[d], v1 = e[16 + d], v2 = e[32 + d], v3 = e[48 + d];
            s0 = fmaf(v0, v0, s0); s1 = fmaf(v1, v1, s1);
            s2 = fmaf(v2, v2, s2); s3 = fmaf(v3, v3, s3);
        }
        eposneg[k] = -0.5f * ((s0 + s1) + (s2 + s3));
    }
}

// ---- K2: main (R15 body, verbatim — proven 53 µs / 56 VGPR) ----------------
__global__ __launch_bounds__(1024)
void vq_main(const float* __restrict__ z_e, const float* __restrict__ emb,
             const short* __restrict__ EF, const float* __restrict__ eposneg,
             float* __restrict__ out, float* __restrict__ acc,
             unsigned int* __restrict__ cnt,
             unsigned long long* __restrict__ wlh, float* __restrict__ wlz,
             unsigned int hcap, unsigned int zcap) {
    extern __shared__ __align__(16) char smem[];
    const int tid = threadIdx.x;

    // stage 64 KB E-fp16 fragments + 2 KB eposneg (coalesced int4 from EF)
    {
        const int4* src = reinterpret_cast<const int4*>(EF);
        int4*       dst = reinterpret_cast<int4*>(smem);
#pragma unroll
        for (int i = 0; i < 4; ++i) dst[tid + i * 1024] = src[tid + i * 1024];
        if (tid < Kc) ((float*)(smem + LDS_EPOS))[tid] = eposneg[tid];
    }
    __syncthreads();
    const float* eposL = (const float*)(smem + LDS_EPOS);

    const int wave = tid >> 6, lane = tid & 63;
    const int p16 = lane & 15, g = lane >> 4;
    const int g4 = g * 4, lane16 = lane * 16;
    const int pbase = blockIdx.x * 512 + wave * 32;      // 32 points per wave
    const int b = pbase >> 12, hw0 = pbase & 4095;
    const float* zbase = z_e + (size_t)b * (Dc * HWc) + hw0;

    // Z fp16 fragments: element j -> Z[d = c*32+g*8+j][point = t*16+p16]
    half8 zh[2][2];
#pragma unroll
    for (int t = 0; t < 2; ++t)
#pragma unroll
        for (int c = 0; c < 2; ++c)
#pragma unroll
            for (int j = 0; j < 8; ++j)
                zh[t][c][j] = (_Float16)zbase[(size_t)(c * 32 + g * 8 + j) * HWc + t * 16 + p16];

    float a1[2] = {-3.4e38f, -3.4e38f}, a2[2] = {-3.4e38f, -3.4e38f};
    int   i1[2] = {0, 0};

#pragma unroll 1
    for (int kt = 0; kt < Kc / 16; ++kt) {
        const char* eb = smem + kt * 2048 + lane16;
        half8 eh0 = *reinterpret_cast<const half8*>(eb);
        half8 eh1 = *reinterpret_cast<const half8*>(eb + 1024);
        f32x4 en = *reinterpret_cast<const f32x4*>(eposL + kt * 16 + g4);
        f32x4 c0, c1;
        c0 = __builtin_amdgcn_mfma_f32_16x16x32_f16(eh0, zh[0][0], en, 0, 0, 0);
        c1 = __builtin_amdgcn_mfma_f32_16x16x32_f16(eh0, zh[1][0], en, 0, 0, 0);
        c0 = __builtin_amdgcn_mfma_f32_16x16x32_f16(eh1, zh[0][1], c0, 0, 0, 0);
        c1 = __builtin_amdgcn_mfma_f32_16x16x32_f16(eh1, zh[1][1], c1, 0, 0, 0);
#pragma unroll
        for (int r = 0; r < 4; ++r) {                    // code ascending in r
            float s0 = c0[r], s1 = c1[r];
            int code = kt * 16 + g4 + r;
            bool gt0 = s0 > a1[0];                       // strict: first-occurrence
            a2[0] = __builtin_amdgcn_fmed3f(a2[0], s0, a1[0]);
            i1[0] = gt0 ? code : i1[0];
            a1[0] = gt0 ? s0 : a1[0];
            bool gt1 = s1 > a1[1];
            a2[1] = __builtin_amdgcn_fmed3f(a2[1], s1, a1[1]);
            i1[1] = gt1 ? code : i1[1];
            a1[1] = gt1 ? s1 : a1[1];
        }
    }

    // merge (a1,i1,a2) across the 4 lane-groups (code subsets), per point
#pragma unroll
    for (int off = 16; off <= 32; off <<= 1)
#pragma unroll
        for (int t = 0; t < 2; ++t) {
            float oa1 = __shfl_xor(a1[t], off, 64);
            float oa2 = __shfl_xor(a2[t], off, 64);
            int   oi1 = __shfl_xor(i1[t], off, 64);
            float lo  = fminf(a1[t], oa1);
            a2[t] = fmaxf(fmaxf(a2[t], oa2), lo);
            bool take = (oa1 > a1[t]) || (oa1 == a1[t] && oi1 < i1[t]);
            a1[t] = take ? oa1 : a1[t];
            i1[t] = take ? oi1 : i1[t];
        }

    // worklist append: header {oldidx, point} + coalesced z fp32 stash
    unsigned m[2];
#pragma unroll
    for (int t = 0; t < 2; ++t) {
        bool flg = (a1[t] - a2[t]) <= FLAG_HALF;         // near-tie in approx metric
        m[t] = (unsigned)(__ballot(g == 0 && flg) & 0xFFFFull);
    }
    unsigned mask = m[0] | (m[1] << 16);
    int npts = __popc(mask);
    unsigned wbase = 0;
    if (lane == 0 && npts) wbase = atomicAdd(cnt, (unsigned)npts);
    wbase = __shfl(wbase, 0, 64);
    unsigned mm = mask;
    int k2 = 0;
    while (mm) {
        int idx = __ffs(mm) - 1; mm &= mm - 1;           // wave-uniform
        unsigned pos = wbase + (unsigned)k2; ++k2;
        if (pos < hcap) {
            int oldi = (idx & 16) ? __shfl(i1[1], idx & 15, 64)
                                  : __shfl(i1[0], idx & 15, 64);
            if (lane == 0)
                wlh[pos] = ((unsigned long long)(unsigned)oldi << 32)
                         | (unsigned)(pbase + idx);
            if (pos < zcap)                              // L1-hot, coalesced stash
                wlz[(size_t)pos * 64 + lane] = zbase[(size_t)lane * HWc + idx];
        }
    }

    // epilogue: gather exact fp32 code rows, write z_q, loss from zh
    float lsum = 0.f;
#pragma unroll
    for (int t = 0; t < 2; ++t) {
        const float* er = emb + (size_t)i1[t] * Dc;
        float* op = out + (size_t)b * (Dc * HWc) + hw0 + t * 16 + p16;
#pragma unroll
        for (int c = 0; c < 2; ++c)
#pragma unroll
            for (int j = 0; j < 8; ++j) {
                int d = c * 32 + g * 8 + j;              // lane's own d-slots
                float e = er[d];
                op[(size_t)d * HWc] = e;
                float f = e - (float)zh[t][c][j];
                lsum = fmaf(f, f, lsum);
            }
    }

    // block-level loss reduction -> one atomic per block
    float v = lsum;
#pragma unroll
    for (int off = 32; off > 0; off >>= 1) v += __shfl_down(v, off);
    float* red = (float*)(smem + LDS_RED);
    if (lane == 0) red[wave] = v;
    __syncthreads();
    if (tid == 0) {
        float bs = 0.f;
#pragma unroll
        for (int w = 0; w < 16; ++w) bs += red[w];
        atomicAdd(acc, bs);
    }
}

// ---- K3: exact fp32 fixup — 512-thr blocks (8 waves share one staging) -----
// Same compute path as R15 (bit-identical decisions); staging traffic halves
// (122 x 128KB instead of 244 x) and amortizes over 8 waves per block.
// No device-scope fences (R17/R18's fused-finalize fence cost ~10 µs on the
// 8-XCD non-coherent-L2 fabric — finalize is a separate tiny kernel again).
__global__ __launch_bounds__(512) void vq_fixup(const float* __restrict__ z_e,
                                                const float* __restrict__ emb,
                                                const float* __restrict__ eposneg,
                                                const unsigned long long* __restrict__ wlh,
                                                const float* __restrict__ wlz,
                                                const unsigned int* __restrict__ cnt,
                                                unsigned int hcap, unsigned int zcap,
                                                float* __restrict__ out,
                                                float* __restrict__ acc) {
    extern __shared__ __align__(16) char fsm[];          // 128KB E-fp32 + 2KB epos
    __shared__ __align__(16) float zsh[8][4][64];        // [wave][slot][dim]
    const unsigned n = min(*cnt, hcap);
    const unsigned nch = (n + 3) >> 2;                   // chunks of 4 points
    if (blockIdx.x * 8 >= nch) return;                   // no work: skip staging

    // stage codebook (XOR-swizzled) + eposneg
    {
        const float4* e4 = reinterpret_cast<const float4*>(emb);
        for (int i = threadIdx.x; i < 8192; i += 512) {
            int row = i >> 4, q = i & 15;
            *reinterpret_cast<float4*>(fsm + row * 256 + ((q ^ (row & 15)) << 4)) = e4[i];
        }
        for (int i = threadIdx.x; i < Kc; i += 512)
            ((float*)(fsm + FX_EPOS))[i] = eposneg[i];
    }
    __syncthreads();
    const float* eposL = (const float*)(fsm + FX_EPOS);

    const int lane = threadIdx.x & 63;
    const int wv   = threadIdx.x >> 6;
    const int swz16 = (lane & 15) << 4;                  // code&15 == lane&15
    const unsigned wid = blockIdx.x * 8 + wv;
    const unsigned nw  = gridDim.x * 8;
    for (unsigned ch = wid; ch < nch; ch += nw) {
        const unsigned base = ch * 4;
        int pp[4], oldi[4];
#pragma unroll
        for (int s = 0; s < 4; ++s) {
            unsigned idx = base + (unsigned)s;
            if (idx >= n) idx = n - 1;                   // pad: dup last entry
            unsigned long long h = wlh[idx];
            pp[s]   = (int)(h & 0xFFFFFFFFull);
            oldi[s] = (int)(h >> 32);
            if (idx < zcap) {
                zsh[wv][s][lane] = wlz[(size_t)idx * 64 + lane];   // coalesced
            } else {
                int b = pp[s] >> 12, hw = pp[s] & 4095;
                zsh[wv][s][lane] = z_e[(size_t)b * (Dc * HWc) + (size_t)lane * HWc + hw];
            }
        }
        asm volatile("s_waitcnt lgkmcnt(0) vmcnt(0)" ::: "memory");

        float bd[4] = {3.4e38f, 3.4e38f, 3.4e38f, 3.4e38f};
        int   bi[4] = {0, 0, 0, 0};
#pragma unroll 1
        for (int r = 0; r < 8; ++r) {                    // codes r*64 + lane
            const int code = r * 64 + lane;
            const uintptr_t ebp = (uintptr_t)fsm + (unsigned)code * 256;
            float s0[4] = {0.f, 0.f, 0.f, 0.f}, s1[4] = {0.f, 0.f, 0.f, 0.f};
            float s2[4] = {0.f, 0.f, 0.f, 0.f}, s3[4] = {0.f, 0.f, 0.f, 0.f};
#pragma unroll
            for (int q = 0; q < 4; ++q) {                // d order 0..15 per chain
                float4 e0 = *reinterpret_cast<const float4*>(ebp + ((( q      << 4)) ^ swz16));
                float4 e1 = *reinterpret_cast<const float4*>(ebp + ((((4 + q) << 4)) ^ swz16));
                float4 e2 = *reinterpret_cast<const float4*>(ebp + ((((8 + q) << 4)) ^ swz16));
                float4 e3 = *reinterpret_cast<const float4*>(ebp + ((((12 + q) << 4)) ^ swz16));
#pragma unroll
                for (int s = 0; s < 4; ++s) {            // 4 points share the e row
                    const float4* z4 = reinterpret_cast<const float4*>(zsh[wv][s]);
                    float4 zz0 = z4[q],      zz1 = z4[4 + q];
                    float4 zz2 = z4[8 + q],  zz3 = z4[12 + q];
                    s0[s] = fmaf(e0.x, zz0.x, s0[s]); s0[s] = fmaf(e0.y, zz0.y, s0[s]);
                    s0[s] = fmaf(e0.z, zz0.z, s0[s]); s0[s] = fmaf(e0.w, zz0.w, s0[s]);
                    s1[s] = fmaf(e1.x, zz1.x, s1[s]); s1[s] = fmaf(e1.y, zz1.y, s1[s]);
                    s1[s] = fmaf(e1.z, zz1.z, s1[s]); s1[s] = fmaf(e1.w, zz1.w, s1[s]);
                    s2[s] = fmaf(e2.x, zz2.x, s2[s]); s2[s] = fmaf(e2.y, zz2.y, s2[s]);
                    s2[s] = fmaf(e2.z, zz2.z, s2[s]); s2[s] = fmaf(e2.w, zz2.w, s2[s]);
                    s3[s] = fmaf(e3.x, zz3.x, s3[s]); s3[s] = fmaf(e3.y, zz3.y, s3[s]);
                    s3[s] = fmaf(e3.z, zz3.z, s3[s]); s3[s] = fmaf(e3.w, zz3.w, s3[s]);
                }
            }
            const float en2 = -2.0f * eposL[code];       // +||e||^2 term
#pragma unroll
            for (int s = 0; s < 4; ++s) {
                float dot  = (s0[s] + s1[s]) + (s2[s] + s3[s]);
                float dist = fmaf(-2.0f, dot, en2);
                bool lt = dist < bd[s];                  // within-lane ascending
                bd[s] = lt ? dist : bd[s];
                bi[s] = lt ? code : bi[s];
            }
        }
        // per-slot cross-lane argmin; patch ONLY if the winner changed
#pragma unroll 1
        for (int s = 0; s < 4; ++s) {
            if (base + (unsigned)s >= n) break;
            float bds = bd[s]; int bis = bi[s];
#pragma unroll
            for (int off = 32; off > 0; off >>= 1) {
                float od = __shfl_xor(bds, off, 64);
                int   oi = __shfl_xor(bis, off, 64);
                bool take = (od < bds) || (od == bds && oi < bis);
                bds = take ? od : bds;
                bis = take ? oi : bis;
            }
            if (bis == oldi[s]) continue;                // approx winner was right
            int p = pp[s];
            int b = p >> 12, hw = p & 4095;
            int qd = lane >> 2, od4 = (lane & 3) << 2;
            float en = *reinterpret_cast<const float*>(
                (uintptr_t)fsm + (unsigned)bis * 256 + (((qd ^ (bis & 15)) << 4) | od4));
            float eo = *reinterpret_cast<const float*>(
                (uintptr_t)fsm + (unsigned)oldi[s] * 256 + (((qd ^ (oldi[s] & 15)) << 4) | od4));
            float zf = zsh[wv][s][lane];
            out[(size_t)b * (Dc * HWc) + (size_t)lane * HWc + hw] = en;
            float dn = en - zf, dold = eo - zf;
            float delta = fmaf(dn, dn, -dold * dold);
#pragma unroll
            for (int off = 32; off > 0; off >>= 1) delta += __shfl_down(delta, off);
            if (lane == 0) atomicAdd(acc, delta);
        }
    }
}

// ---- K4: finalize loss (separate tiny kernel — NO device-scope fences) -----
__global__ void vq_finalize(const float* __restrict__ acc, float* __restrict__ out_loss) {
    out_loss[0] = 1.25f * (acc[0] * INV_ELEMS);
}

extern "C" void kernel_launch(void* const* d_in, const int* in_sizes, int n_in,
                              void* d_out, int out_size, void* d_ws, size_t ws_size,
                              hipStream_t stream) {
    const float* z_e = (const float*)d_in[0];
    const float* emb = (const float*)d_in[1];
    float* out = (float*)d_out;

    char* ws = (char*)d_ws;
    float*              acc     = (float*)(ws);          // 4 B
    unsigned*           cnt     = (unsigned*)(ws + 4);   // 4 B worklist counter
    float*              eposneg = (float*)(ws + 256);    // 512 f32 = 2 KB
    short*              EF      = (short*)(ws + 4096);   // 64 KB fp16 fragments
    unsigned long long* wlh     = (unsigned long long*)(ws + WL_H_OFF);
    float*              wlz     = (float*)(ws + WL_Z_OFF);

    unsigned hcap = 0, zcap = 0;
    if (ws_size > (size_t)WL_H_OFF + 8)
        hcap = (unsigned)min((size_t)32768, (ws_size - WL_H_OFF) / 8);
    if (ws_size > (size_t)WL_Z_OFF + 256)
        zcap = (unsigned)min((size_t)32768, (ws_size - WL_Z_OFF) / 256);

    hipFuncSetAttribute(reinterpret_cast<const void*>(vq_main),
                        hipFuncAttributeMaxDynamicSharedMemorySize, LDS_TOT);
    hipFuncSetAttribute(reinterpret_cast<const void*>(vq_fixup),
                        hipFuncAttributeMaxDynamicSharedMemorySize, FX_TOT);

    hipMemsetAsync(ws, 0, 8, stream);                    // acc + cnt
    vq_prep<<<18, 256, 0, stream>>>(emb, EF, eposneg);
    vq_main<<<Nc / 512, 1024, LDS_TOT, stream>>>(z_e, emb, EF, eposneg, out, acc,
                                                 cnt, wlh, wlz, hcap, zcap);
    vq_fixup<<<128, 512, FX_TOT, stream>>>(z_e, emb, eposneg, wlh, wlz, cnt,
                                           hcap, zcap, out, acc);
    vq_finalize<<<1, 1, 0, stream>>>(acc, out + (size_t)Nc * Dc);
}

// Round 20
// 81.990 us; speedup vs baseline: 1.4790x; 1.4790x over previous
//
#include <hip/hip_runtime.h>

// z_e: [B=64, D=64, H=64, W=64] fp32 ; embeddings: [K=512, D=64] fp32
// out: z_q_st [64,64,64,64] fp32 ++ loss (1 fp32)
constexpr int Dc  = 64;
constexpr int Kc  = 512;
constexpr int HWc = 4096;
constexpr int Nc  = 64 * HWc;                    // 262144 points
constexpr float INV_ELEMS = 1.0f / 16777216.0f;
// fp16 1-term metric: s = eh.zh - ||e||^2/2. FLAG_HALF = 0.02 ~ 7.8 sigma of
// the pairwise error; flagged points get exact fp32 rescan. Rate ~1.5%.
constexpr float FLAG_HALF = 0.02f;

constexpr int LDS_EPOS = 65536;                  // vq_main: after 64KB E-fp16
constexpr int LDS_RED  = LDS_EPOS + 2048;
constexpr int LDS_TOT  = LDS_RED + 64;           // 67648 B -> 2 blocks/CU

constexpr int FX_EPOS  = 131072;                 // vq_fixup: after 128KB E-fp32
constexpr int FX_TOT   = FX_EPOS + 2048;         // 133120 B -> 1 block/CU

constexpr int WL_H_OFF = 69632;                  // headers: {oldidx, point} u64
constexpr int WL_Z_OFF = WL_H_OFF + 262144;      // stashed z: 64 f32 per entry

typedef __attribute__((ext_vector_type(8))) _Float16 half8;
typedef __attribute__((ext_vector_type(4))) float    f32x4;

static __device__ __forceinline__ short f2h(float x) {   // RNE fp32->fp16
    _Float16 h = (_Float16)x;
    return __builtin_bit_cast(short, h);
}

// ---- K1: prep — pack E-fp16 fragment stream (64KB) + eposneg ---------------
__global__ __launch_bounds__(256) void vq_prep(const float* __restrict__ emb,
                                               short* __restrict__ EF,
                                               float* __restrict__ eposneg) {
    int q = blockIdx.x * 256 + threadIdx.x;
    if (q < 4096) {
        int kt = q >> 7, c = (q >> 6) & 1, lane = q & 63;
        int code = kt * 16 + (lane & 15);
        int d0   = c * 32 + (lane >> 4) * 8;
        const float* e = emb + (size_t)code * Dc + d0;
        short v[8];
#pragma unroll
        for (int j = 0; j < 8; ++j) v[j] = f2h(e[j]);
        *reinterpret_cast<int4*>(EF + (size_t)q * 8) = *reinterpret_cast<int4*>(v);
    } else if (q < 4096 + Kc) {
        int k = q - 4096;
        const float* e = emb + (size_t)k * Dc;
        float s0 = 0.f, s1 = 0.f, s2 = 0.f, s3 = 0.f;
#pragma unroll
        for (int d = 0; d < 16; ++d) {
            float v0 = e[d], v1 = e[16 + d], v2 = e[32 + d], v3 = e[48 + d];
            s0 = fmaf(v0, v0, s0); s1 = fmaf(v1, v1, s1);
            s2 = fmaf(v2, v2, s2); s3 = fmaf(v3, v3, s3);
        }
        eposneg[k] = -0.5f * ((s0 + s1) + (s2 + s3));
    }
}

// ---- K2: main (R15 body, verbatim — proven 53 µs / 56 VGPR) ----------------
__global__ __launch_bounds__(1024)
void vq_main(const float* __restrict__ z_e, const float* __restrict__ emb,
             const short* __restrict__ EF, const float* __restrict__ eposneg,
             float* __restrict__ out, float* __restrict__ acc,
             unsigned int* __restrict__ cnt,
             unsigned long long* __restrict__ wlh, float* __restrict__ wlz,
             unsigned int hcap, unsigned int zcap) {
    extern __shared__ __align__(16) char smem[];
    const int tid = threadIdx.x;

    // stage 64 KB E-fp16 fragments + 2 KB eposneg (coalesced int4 from EF)
    {
        const int4* src = reinterpret_cast<const int4*>(EF);
        int4*       dst = reinterpret_cast<int4*>(smem);
#pragma unroll
        for (int i = 0; i < 4; ++i) dst[tid + i * 1024] = src[tid + i * 1024];
        if (tid < Kc) ((float*)(smem + LDS_EPOS))[tid] = eposneg[tid];
    }
    __syncthreads();
    const float* eposL = (const float*)(smem + LDS_EPOS);

    const int wave = tid >> 6, lane = tid & 63;
    const int p16 = lane & 15, g = lane >> 4;
    const int g4 = g * 4, lane16 = lane * 16;
    const int pbase = blockIdx.x * 512 + wave * 32;      // 32 points per wave
    const int b = pbase >> 12, hw0 = pbase & 4095;
    const float* zbase = z_e + (size_t)b * (Dc * HWc) + hw0;

    // Z fp16 fragments: element j -> Z[d = c*32+g*8+j][point = t*16+p16]
    half8 zh[2][2];
#pragma unroll
    for (int t = 0; t < 2; ++t)
#pragma unroll
        for (int c = 0; c < 2; ++c)
#pragma unroll
            for (int j = 0; j < 8; ++j)
                zh[t][c][j] = (_Float16)zbase[(size_t)(c * 32 + g * 8 + j) * HWc + t * 16 + p16];

    float a1[2] = {-3.4e38f, -3.4e38f}, a2[2] = {-3.4e38f, -3.4e38f};
    int   i1[2] = {0, 0};

#pragma unroll 1
    for (int kt = 0; kt < Kc / 16; ++kt) {
        const char* eb = smem + kt * 2048 + lane16;
        half8 eh0 = *reinterpret_cast<const half8*>(eb);
        half8 eh1 = *reinterpret_cast<const half8*>(eb + 1024);
        f32x4 en = *reinterpret_cast<const f32x4*>(eposL + kt * 16 + g4);
        f32x4 c0, c1;
        c0 = __builtin_amdgcn_mfma_f32_16x16x32_f16(eh0, zh[0][0], en, 0, 0, 0);
        c1 = __builtin_amdgcn_mfma_f32_16x16x32_f16(eh0, zh[1][0], en, 0, 0, 0);
        c0 = __builtin_amdgcn_mfma_f32_16x16x32_f16(eh1, zh[0][1], c0, 0, 0, 0);
        c1 = __builtin_amdgcn_mfma_f32_16x16x32_f16(eh1, zh[1][1], c1, 0, 0, 0);
#pragma unroll
        for (int r = 0; r < 4; ++r) {                    // code ascending in r
            float s0 = c0[r], s1 = c1[r];
            int code = kt * 16 + g4 + r;
            bool gt0 = s0 > a1[0];                       // strict: first-occurrence
            a2[0] = __builtin_amdgcn_fmed3f(a2[0], s0, a1[0]);
            i1[0] = gt0 ? code : i1[0];
            a1[0] = gt0 ? s0 : a1[0];
            bool gt1 = s1 > a1[1];
            a2[1] = __builtin_amdgcn_fmed3f(a2[1], s1, a1[1]);
            i1[1] = gt1 ? code : i1[1];
            a1[1] = gt1 ? s1 : a1[1];
        }
    }

    // merge (a1,i1,a2) across the 4 lane-groups (code subsets), per point
#pragma unroll
    for (int off = 16; off <= 32; off <<= 1)
#pragma unroll
        for (int t = 0; t < 2; ++t) {
            float oa1 = __shfl_xor(a1[t], off, 64);
            float oa2 = __shfl_xor(a2[t], off, 64);
            int   oi1 = __shfl_xor(i1[t], off, 64);
            float lo  = fminf(a1[t], oa1);
            a2[t] = fmaxf(fmaxf(a2[t], oa2), lo);
            bool take = (oa1 > a1[t]) || (oa1 == a1[t] && oi1 < i1[t]);
            a1[t] = take ? oa1 : a1[t];
            i1[t] = take ? oi1 : i1[t];
        }

    // worklist append: header {oldidx, point} + coalesced z fp32 stash
    unsigned m[2];
#pragma unroll
    for (int t = 0; t < 2; ++t) {
        bool flg = (a1[t] - a2[t]) <= FLAG_HALF;         // near-tie in approx metric
        m[t] = (unsigned)(__ballot(g == 0 && flg) & 0xFFFFull);
    }
    unsigned mask = m[0] | (m[1] << 16);
    int npts = __popc(mask);
    unsigned wbase = 0;
    if (lane == 0 && npts) wbase = atomicAdd(cnt, (unsigned)npts);
    wbase = __shfl(wbase, 0, 64);
    unsigned mm = mask;
    int k2 = 0;
    while (mm) {
        int idx = __ffs(mm) - 1; mm &= mm - 1;           // wave-uniform
        unsigned pos = wbase + (unsigned)k2; ++k2;
        if (pos < hcap) {
            int oldi = (idx & 16) ? __shfl(i1[1], idx & 15, 64)
                                  : __shfl(i1[0], idx & 15, 64);
            if (lane == 0)
                wlh[pos] = ((unsigned long long)(unsigned)oldi << 32)
                         | (unsigned)(pbase + idx);
            if (pos < zcap)                              // L1-hot, coalesced stash
                wlz[(size_t)pos * 64 + lane] = zbase[(size_t)lane * HWc + idx];
        }
    }

    // epilogue: gather exact fp32 code rows, write z_q, loss from zh
    float lsum = 0.f;
#pragma unroll
    for (int t = 0; t < 2; ++t) {
        const float* er = emb + (size_t)i1[t] * Dc;
        float* op = out + (size_t)b * (Dc * HWc) + hw0 + t * 16 + p16;
#pragma unroll
        for (int c = 0; c < 2; ++c)
#pragma unroll
            for (int j = 0; j < 8; ++j) {
                int d = c * 32 + g * 8 + j;              // lane's own d-slots
                float e = er[d];
                op[(size_t)d * HWc] = e;
                float f = e - (float)zh[t][c][j];
                lsum = fmaf(f, f, lsum);
            }
    }

    // block-level loss reduction -> one atomic per block
    float v = lsum;
#pragma unroll
    for (int off = 32; off > 0; off >>= 1) v += __shfl_down(v, off);
    float* red = (float*)(smem + LDS_RED);
    if (lane == 0) red[wave] = v;
    __syncthreads();
    if (tid == 0) {
        float bs = 0.f;
#pragma unroll
        for (int w = 0; w < 16; ++w) bs += red[w];
        atomicAdd(acc, bs);
    }
}

// ---- K3: exact fp32 fixup (R15 body, verbatim: grid 256 x 256 thr) ---------
// Many small blocks (4 waves each) hide staging latency by breadth; no
// device-scope fences (fence-finalize cost ~15 µs on the 8-XCD fabric).
__global__ __launch_bounds__(256) void vq_fixup(const float* __restrict__ z_e,
                                                const float* __restrict__ emb,
                                                const float* __restrict__ eposneg,
                                                const unsigned long long* __restrict__ wlh,
                                                const float* __restrict__ wlz,
                                                const unsigned int* __restrict__ cnt,
                                                unsigned int hcap, unsigned int zcap,
                                                float* __restrict__ out,
                                                float* __restrict__ acc) {
    extern __shared__ __align__(16) char fsm[];          // 128KB E-fp32 + 2KB epos
    __shared__ __align__(16) float zsh[4][4][64];        // [wave][slot][dim]
    const unsigned n = min(*cnt, hcap);
    const unsigned nch = (n + 3) >> 2;                   // chunks of 4 points
    if (blockIdx.x * 4 >= nch) return;                   // no work: skip staging

    // stage codebook (XOR-swizzled) + eposneg
    {
        const float4* e4 = reinterpret_cast<const float4*>(emb);
        for (int i = threadIdx.x; i < 8192; i += 256) {
            int row = i >> 4, q = i & 15;
            *reinterpret_cast<float4*>(fsm + row * 256 + ((q ^ (row & 15)) << 4)) = e4[i];
        }
        for (int i = threadIdx.x; i < Kc; i += 256)
            ((float*)(fsm + FX_EPOS))[i] = eposneg[i];
    }
    __syncthreads();
    const float* eposL = (const float*)(fsm + FX_EPOS);

    const int lane = threadIdx.x & 63;
    const int wv   = threadIdx.x >> 6;
    const int swz16 = (lane & 15) << 4;                  // code&15 == lane&15
    const unsigned wid = blockIdx.x * 4 + wv;
    const unsigned nw  = gridDim.x * 4;
    for (unsigned ch = wid; ch < nch; ch += nw) {
        const unsigned base = ch * 4;
        int pp[4], oldi[4];
#pragma unroll
        for (int s = 0; s < 4; ++s) {
            unsigned idx = base + (unsigned)s;
            if (idx >= n) idx = n - 1;                   // pad: dup last entry
            unsigned long long h = wlh[idx];
            pp[s]   = (int)(h & 0xFFFFFFFFull);
            oldi[s] = (int)(h >> 32);
            if (idx < zcap) {
                zsh[wv][s][lane] = wlz[(size_t)idx * 64 + lane];   // coalesced
            } else {
                int b = pp[s] >> 12, hw = pp[s] & 4095;
                zsh[wv][s][lane] = z_e[(size_t)b * (Dc * HWc) + (size_t)lane * HWc + hw];
            }
        }
        asm volatile("s_waitcnt lgkmcnt(0) vmcnt(0)" ::: "memory");

        float bd[4] = {3.4e38f, 3.4e38f, 3.4e38f, 3.4e38f};
        int   bi[4] = {0, 0, 0, 0};
#pragma unroll 1
        for (int r = 0; r < 8; ++r) {                    // codes r*64 + lane
            const int code = r * 64 + lane;
            const uintptr_t ebp = (uintptr_t)fsm + (unsigned)code * 256;
            float s0[4] = {0.f, 0.f, 0.f, 0.f}, s1[4] = {0.f, 0.f, 0.f, 0.f};
            float s2[4] = {0.f, 0.f, 0.f, 0.f}, s3[4] = {0.f, 0.f, 0.f, 0.f};
#pragma unroll
            for (int q = 0; q < 4; ++q) {                // d order 0..15 per chain
                float4 e0 = *reinterpret_cast<const float4*>(ebp + ((( q      << 4)) ^ swz16));
                float4 e1 = *reinterpret_cast<const float4*>(ebp + ((((4 + q) << 4)) ^ swz16));
                float4 e2 = *reinterpret_cast<const float4*>(ebp + ((((8 + q) << 4)) ^ swz16));
                float4 e3 = *reinterpret_cast<const float4*>(ebp + ((((12 + q) << 4)) ^ swz16));
#pragma unroll
                for (int s = 0; s < 4; ++s) {            // 4 points share the e row
                    const float4* z4 = reinterpret_cast<const float4*>(zsh[wv][s]);
                    float4 zz0 = z4[q],      zz1 = z4[4 + q];
                    float4 zz2 = z4[8 + q],  zz3 = z4[12 + q];
                    s0[s] = fmaf(e0.x, zz0.x, s0[s]); s0[s] = fmaf(e0.y, zz0.y, s0[s]);
                    s0[s] = fmaf(e0.z, zz0.z, s0[s]); s0[s] = fmaf(e0.w, zz0.w, s0[s]);
                    s1[s] = fmaf(e1.x, zz1.x, s1[s]); s1[s] = fmaf(e1.y, zz1.y, s1[s]);
                    s1[s] = fmaf(e1.z, zz1.z, s1[s]); s1[s] = fmaf(e1.w, zz1.w, s1[s]);
                    s2[s] = fmaf(e2.x, zz2.x, s2[s]); s2[s] = fmaf(e2.y, zz2.y, s2[s]);
                    s2[s] = fmaf(e2.z, zz2.z, s2[s]); s2[s] = fmaf(e2.w, zz2.w, s2[s]);
                    s3[s] = fmaf(e3.x, zz3.x, s3[s]); s3[s] = fmaf(e3.y, zz3.y, s3[s]);
                    s3[s] = fmaf(e3.z, zz3.z, s3[s]); s3[s] = fmaf(e3.w, zz3.w, s3[s]);
                }
            }
            const float en2 = -2.0f * eposL[code];       // +||e||^2 term
#pragma unroll
            for (int s = 0; s < 4; ++s) {
                float dot  = (s0[s] + s1[s]) + (s2[s] + s3[s]);
                float dist = fmaf(-2.0f, dot, en2);
                bool lt = dist < bd[s];                  // within-lane ascending
                bd[s] = lt ? dist : bd[s];
                bi[s] = lt ? code : bi[s];
            }
        }
        // per-slot cross-lane argmin; patch ONLY if the winner changed
#pragma unroll 1
        for (int s = 0; s < 4; ++s) {
            if (base + (unsigned)s >= n) break;
            float bds = bd[s]; int bis = bi[s];
#pragma unroll
            for (int off = 32; off > 0; off >>= 1) {
                float od = __shfl_xor(bds, off, 64);
                int   oi = __shfl_xor(bis, off, 64);
                bool take = (od < bds) || (od == bds && oi < bis);
                bds = take ? od : bds;
                bis = take ? oi : bis;
            }
            if (bis == oldi[s]) continue;                // approx winner was right
            int p = pp[s];
            int b = p >> 12, hw = p & 4095;
            int qd = lane >> 2, od4 = (lane & 3) << 2;
            float en = *reinterpret_cast<const float*>(
                (uintptr_t)fsm + (unsigned)bis * 256 + (((qd ^ (bis & 15)) << 4) | od4));
            float eo = *reinterpret_cast<const float*>(
                (uintptr_t)fsm + (unsigned)oldi[s] * 256 + (((qd ^ (oldi[s] & 15)) << 4) | od4));
            float zf = zsh[wv][s][lane];
            out[(size_t)b * (Dc * HWc) + (size_t)lane * HWc + hw] = en;
            float dn = en - zf, dold = eo - zf;
            float delta = fmaf(dn, dn, -dold * dold);
#pragma unroll
            for (int off = 32; off > 0; off >>= 1) delta += __shfl_down(delta, off);
            if (lane == 0) atomicAdd(acc, delta);
        }
    }
}

// ---- K4: finalize loss -----------------------------------------------------
__global__ void vq_finalize(const float* __restrict__ acc, float* __restrict__ out_loss) {
    out_loss[0] = 1.25f * (acc[0] * INV_ELEMS);
}

extern "C" void kernel_launch(void* const* d_in, const int* in_sizes, int n_in,
                              void* d_out, int out_size, void* d_ws, size_t ws_size,
                              hipStream_t stream) {
    const float* z_e = (const float*)d_in[0];
    const float* emb = (const float*)d_in[1];
    float* out = (float*)d_out;

    char* ws = (char*)d_ws;
    float*              acc     = (float*)(ws);          // 4 B
    unsigned*           cnt     = (unsigned*)(ws + 4);   // 4 B worklist counter
    float*              eposneg = (float*)(ws + 256);    // 512 f32 = 2 KB
    short*              EF      = (short*)(ws + 4096);   // 64 KB fp16 fragments
    unsigned long long* wlh     = (unsigned long long*)(ws + WL_H_OFF);
    float*              wlz     = (float*)(ws + WL_Z_OFF);

    unsigned hcap = 0, zcap = 0;
    if (ws_size > (size_t)WL_H_OFF + 8)
        hcap = (unsigned)min((size_t)32768, (ws_size - WL_H_OFF) / 8);
    if (ws_size > (size_t)WL_Z_OFF + 256)
        zcap = (unsigned)min((size_t)32768, (ws_size - WL_Z_OFF) / 256);

    hipFuncSetAttribute(reinterpret_cast<const void*>(vq_main),
                        hipFuncAttributeMaxDynamicSharedMemorySize, LDS_TOT);
    hipFuncSetAttribute(reinterpret_cast<const void*>(vq_fixup),
                        hipFuncAttributeMaxDynamicSharedMemorySize, FX_TOT);

    hipMemsetAsync(ws, 0, 8, stream);                    // acc + cnt
    vq_prep<<<18, 256, 0, stream>>>(emb, EF, eposneg);
    vq_main<<<Nc / 512, 1024, LDS_TOT, stream>>>(z_e, emb, EF, eposneg, out, acc,
                                                 cnt, wlh, wlz, hcap, zcap);
    vq_fixup<<<256, 256, FX_TOT, stream>>>(z_e, emb, eposneg, wlh, wlz, cnt,
                                           hcap, zcap, out, acc);
    vq_finalize<<<1, 1, 0, stream>>>(acc, out + (size_t)Nc * Dc);
}